// Round 7
// baseline (73.891 us; speedup 1.0000x reference)
//
#include <hip/hip_runtime.h>
#include <stdint.h>

#define B_  16
#define H_  512
#define W_  512
#define HW_ (H_*W_)
#define N_  (B_*HW_)

#define TX 64
#define TY 32
#define NBLK 2048

#define G0 0.054488685f
#define G1 0.244201342f
#define G2 0.402619947f

// All planes: col c <-> x = tx0-8+c, stride 80 floats/elems.
// t    [42][80] f32 : row r <-> (reflect-staged) y = ty0-5+r
// blur [38][80] f32 : row r <-> y = ty0-3+r   (+1-quad guards front/back)
// mag  [36][80] f32 : row r <-> y = ty0-2+r   (squared magnitude)
// off  [36][80] i16 : NMS neighbor element-offset (dy*80+dx)
// e    [34][80] u8  : row r <-> y = ty0-1+r   (0/1/2 class)

__device__ __forceinline__ int reflect512(int i) {
    i = i < 0 ? -i : i;
    return i > 511 ? 1022 - i : i;
}
__device__ __forceinline__ int clamp511(int v) {
    return v < 0 ? 0 : (v > 511 ? 511 : v);
}

__global__ __launch_bounds__(256, 4)
void k_canny(const float* __restrict__ pred, const float* __restrict__ sketch,
             const float* __restrict__ matte, float* __restrict__ partials) {
    __shared__ __align__(16) union {
        float t[42*80];
        float mag[36*80];
    } uA;
    __shared__ __align__(16) union {
        float blur_raw[4 + 38*80 + 4];
        uint8_t e[34*80];
    } uB;
    __shared__ __align__(8) short sOff[36*80];
    __shared__ float wsum[4];

    float* const tpl = uA.t;
    float* const mag = uA.mag;
    float* const blr = uB.blur_raw + 4;   // +-1 quad guards
    uint8_t* const e8 = uB.e;

    const int tid = threadIdx.x;
    const int tx0 = blockIdx.x * TX;
    const int ty0 = blockIdx.y * TY;
    const int b   = blockIdx.z;
    const bool xint = (blockIdx.x >= 1) & (blockIdx.x <= 6);
    const bool yint = (blockIdx.y >= 1) & (blockIdx.y <= 14);

    const float* pb = pred   + (size_t)b * 3 * HW_;
    const float* mb = matte  + (size_t)b * HW_;
    const float* sb = sketch + (size_t)b * HW_;

    // ---- A+B1: gray in regs -> horizontal 5-tap -> t[42][80] ----
    if (tid < 210) {
        int r = tid / 5, k = tid - (tid / 5) * 5;   // 42 rows x 5 runs of 16 px
        int ys = reflect512(ty0 - 5 + r);
        const float* prow = pb + ys*W_;
        const float* mrow = mb + ys*W_;
        int xb = tx0 - 12 + 16*k;                   // aligned window base (24 floats)
        float g[24];
        if (xint) {
            #pragma unroll
            for (int qq = 0; qq < 6; ++qq) {
                float4 p0 = *(const float4*)(prow + xb + 4*qq);
                float4 p1 = *(const float4*)(prow + HW_ + xb + 4*qq);
                float4 p2 = *(const float4*)(prow + 2*HW_ + xb + 4*qq);
                float4 m4 = *(const float4*)(mrow + xb + 4*qq);
                g[4*qq+0] = (p0.x+p1.x+p2.x)*m4.x*(1.f/3.f);
                g[4*qq+1] = (p0.y+p1.y+p2.y)*m4.y*(1.f/3.f);
                g[4*qq+2] = (p0.z+p1.z+p2.z)*m4.z*(1.f/3.f);
                g[4*qq+3] = (p0.w+p1.w+p2.w)*m4.w*(1.f/3.f);
            }
        } else {
            #pragma unroll
            for (int i = 0; i < 24; ++i) {
                int xs = reflect512(xb + i);
                g[i] = (prow[xs] + prow[HW_+xs] + prow[2*HW_+xs]) * mrow[xs] * (1.f/3.f);
            }
        }
        // t col 16k+j  <->  x = tx0-8+16k+j ; gray reg idx = j+4, taps j+2..j+6
        int tb = r*80 + 16*k;
        #pragma unroll
        for (int qq = 0; qq < 4; ++qq) {
            int j = 4*qq;
            float4 o;
            o.x = G0*(g[j+2]+g[j+6]) + G1*(g[j+3]+g[j+5]) + G2*g[j+4];
            o.y = G0*(g[j+3]+g[j+7]) + G1*(g[j+4]+g[j+6]) + G2*g[j+5];
            o.z = G0*(g[j+4]+g[j+8]) + G1*(g[j+5]+g[j+7]) + G2*g[j+6];
            o.w = G0*(g[j+5]+g[j+9]) + G1*(g[j+6]+g[j+8]) + G2*g[j+7];
            *(float4*)&tpl[tb + j] = o;
        }
    }
    __syncthreads();

    // ---- B2: vertical 5-tap, flat-quad contiguous b128 -> blur[38][80] ----
    if (yint) {
        for (int j = tid; j < 760; j += 256) {
            float4 a = *(float4*)&tpl[4*j];
            float4 bq = *(float4*)&tpl[4*j + 80];
            float4 c = *(float4*)&tpl[4*j + 160];
            float4 d = *(float4*)&tpl[4*j + 240];
            float4 ee = *(float4*)&tpl[4*j + 320];
            float4 o;
            o.x = G0*(a.x+ee.x) + G1*(bq.x+d.x) + G2*c.x;
            o.y = G0*(a.y+ee.y) + G1*(bq.y+d.y) + G2*c.y;
            o.z = G0*(a.z+ee.z) + G1*(bq.z+d.z) + G2*c.z;
            o.w = G0*(a.w+ee.w) + G1*(bq.w+d.w) + G2*c.w;
            *(float4*)&blr[4*j] = o;
        }
    } else {
        for (int j = tid; j < 760; j += 256) {
            int r = j / 20, q = j - (j / 20) * 20;
            int yc = clamp511(ty0 - 3 + r);
            int r0 = reflect512(yc-2) - ty0 + 5;
            int r1 = reflect512(yc-1) - ty0 + 5;
            int r2 = yc - ty0 + 5;
            int r3 = reflect512(yc+1) - ty0 + 5;
            int r4 = reflect512(yc+2) - ty0 + 5;
            int cq = 4*q;
            float4 a = *(float4*)&tpl[r0*80 + cq];
            float4 bq = *(float4*)&tpl[r1*80 + cq];
            float4 c = *(float4*)&tpl[r2*80 + cq];
            float4 d = *(float4*)&tpl[r3*80 + cq];
            float4 ee = *(float4*)&tpl[r4*80 + cq];
            float4 o;
            o.x = G0*(a.x+ee.x) + G1*(bq.x+d.x) + G2*c.x;
            o.y = G0*(a.y+ee.y) + G1*(bq.y+d.y) + G2*c.y;
            o.z = G0*(a.z+ee.z) + G1*(bq.z+d.z) + G2*c.z;
            o.w = G0*(a.w+ee.w) + G1*(bq.w+d.w) + G2*c.w;
            *(float4*)&blr[4*j] = o;
        }
    }
    __syncthreads();

    // ---- C: sobel -> mag² + off, flat-quad (t dead -> mag aliases it) ----
    if (xint & yint) {
        for (int j = tid; j < 720; j += 256) {
            int f = 4*j;
            float4 am = *(float4*)&blr[f-4];
            float4 ac = *(float4*)&blr[f];
            float4 ap = *(float4*)&blr[f+4];
            float4 bm = *(float4*)&blr[f+76];
            float4 bc = *(float4*)&blr[f+80];
            float4 bp = *(float4*)&blr[f+84];
            float4 cm = *(float4*)&blr[f+156];
            float4 cc = *(float4*)&blr[f+160];
            float4 cp = *(float4*)&blr[f+164];
            float wa[12] = {am.x,am.y,am.z,am.w, ac.x,ac.y,ac.z,ac.w, ap.x,ap.y,ap.z,ap.w};
            float wb[12] = {bm.x,bm.y,bm.z,bm.w, bc.x,bc.y,bc.z,bc.w, bp.x,bp.y,bp.z,bp.w};
            float wc[12] = {cm.x,cm.y,cm.z,cm.w, cc.x,cc.y,cc.z,cc.w, cp.x,cp.y,cp.z,cp.w};
            float4 m2v; int o[4];
            #pragma unroll
            for (int e2 = 0; e2 < 4; ++e2) {
                float a00 = wa[3+e2], a01 = wa[4+e2], a02 = wa[5+e2];
                float a10 = wb[3+e2],                 a12 = wb[5+e2];
                float a20 = wc[3+e2], a21 = wc[4+e2], a22 = wc[5+e2];
                float gxv = (a02 + 2.f*a12 + a22) - (a00 + 2.f*a10 + a20);
                float gyv = (a20 + 2.f*a21 + a22) - (a00 + 2.f*a01 + a02);
                float m2 = fmaf(gxv*gxv + gyv*gyv, 0.015625f, 1e-6f);
                float agx = fabsf(gxv), agy = fabsf(gyv);
                int off;
                if      (agy <= 0.41421356f*agx) off = (gxv >= 0.f) ? 1 : -1;
                else if (agy >= 2.41421356f*agx) off = (gyv > 0.f) ? -80 : 80;
                else off = ((gyv > 0.f) ? -80 : 80) + ((gxv > 0.f) ? 1 : -1);
                ((float*)&m2v)[e2] = m2;
                o[e2] = off;
            }
            *(float4*)&mag[f] = m2v;
            uint2 ow;
            ow.x = (uint32_t)(uint16_t)(short)o[0] | ((uint32_t)(uint16_t)(short)o[1] << 16);
            ow.y = (uint32_t)(uint16_t)(short)o[2] | ((uint32_t)(uint16_t)(short)o[3] << 16);
            *(uint2*)&sOff[f] = ow;
        }
    } else {
        for (int j = tid; j < 720; j += 256) {
            int r = j / 20, q = j - (j / 20) * 20;
            int f = 4*j;
            int y = ty0 - 2 + r;
            #pragma unroll
            for (int e2 = 0; e2 < 4; ++e2) {
                int x = tx0 - 8 + 4*q + e2;
                float m2 = 0.f; int off = 0;
                if ((unsigned)y < 512u && (unsigned)x < 512u) {
                    int r0 = clamp511(y-1) - ty0 + 3;
                    int r1 = y - ty0 + 3;
                    int r2 = clamp511(y+1) - ty0 + 3;
                    int cmm = clamp511(x-1) - tx0 + 8;
                    int ccc = x - tx0 + 8;
                    int cpp = clamp511(x+1) - tx0 + 8;
                    float a00 = blr[r0*80+cmm], a01 = blr[r0*80+ccc], a02 = blr[r0*80+cpp];
                    float a10 = blr[r1*80+cmm],                       a12 = blr[r1*80+cpp];
                    float a20 = blr[r2*80+cmm], a21 = blr[r2*80+ccc], a22 = blr[r2*80+cpp];
                    float gxv = (a02 + 2.f*a12 + a22) - (a00 + 2.f*a10 + a20);
                    float gyv = (a20 + 2.f*a21 + a22) - (a00 + 2.f*a01 + a02);
                    m2 = fmaf(gxv*gxv + gyv*gyv, 0.015625f, 1e-6f);
                    float agx = fabsf(gxv), agy = fabsf(gyv);
                    if      (agy <= 0.41421356f*agx) off = (gxv >= 0.f) ? 1 : -1;
                    else if (agy >= 2.41421356f*agx) off = (gyv > 0.f) ? -80 : 80;
                    else off = ((gyv > 0.f) ? -80 : 80) + ((gxv > 0.f) ? 1 : -1);
                }
                mag[f+e2] = m2;
                sOff[f+e2] = (short)off;
            }
        }
    }
    __syncthreads();

    // ---- D: NMS + double threshold -> e[34][80] bytes (blur dead -> e aliases it) ----
    for (int j = tid; j < 612; j += 256) {
        int r = j / 18, qq = j - (j / 18) * 18 + 1;   // quads 1..18 (cols 4..75)
        int f = (r+1)*80 + 4*qq;                      // mag row r+1
        float4 m2q = *(float4*)&mag[f];
        uint2 ow = *(uint2*)&sOff[f];
        int ov[4] = { (int)(short)(ow.x & 0xFFFFu), (int)(short)(ow.x >> 16),
                      (int)(short)(ow.y & 0xFFFFu), (int)(short)(ow.y >> 16) };
        float mv[4] = {m2q.x, m2q.y, m2q.z, m2q.w};
        uint32_t pack = 0;
        #pragma unroll
        for (int e2 = 0; e2 < 4; ++e2) {
            float m2 = mv[e2];
            float n1 = mag[f + e2 + ov[e2]];
            float n2 = mag[f + e2 - ov[e2]];
            int cls = 0;
            if (m2 > n1 && m2 > n2) cls = (m2 > 0.01f) + (m2 > 0.04f);
            pack |= (uint32_t)cls << (8*e2);
        }
        *(uint32_t*)&e8[r*80 + 4*qq] = pack;
    }
    __syncthreads();

    // ---- E: guarded 1-sweep hysteresis + MSE, 2 quads/thread ----
    {
        float lacc = 0.f;
        #pragma unroll
        for (int half = 0; half < 2; ++half) {
            int uq = tid + half*256;
            int r = uq >> 4, q16 = uq & 15;
            int gy = ty0 + r, gx = tx0 + q16*4;
            int ei = (r+1)*80 + 8 + q16*4;
            uint32_t w = *(uint32_t*)&e8[ei];
            int cls[4] = { (int)(w & 255u), (int)((w>>8) & 255u),
                           (int)((w>>16) & 255u), (int)((w>>24) & 255u) };
            uint32_t twk = w ^ 0x01010101u;
            if ((twk - 0x01010101u) & ~twk & 0x80808080u) {   // any weak byte
                #pragma unroll
                for (int jj = 0; jj < 4; ++jj) {
                    if (cls[jj] == 1) {
                        int cc = ei + jj;
                        bool pr = (e8[cc-81]==2) | (e8[cc-80]==2) | (e8[cc-79]==2)
                                | (e8[cc-1] ==2) |                  (e8[cc+1] ==2)
                                | (e8[cc+79]==2) | (e8[cc+80]==2) | (e8[cc+81]==2);
                        if (pr) cls[jj] = 2;
                    }
                }
            }
            float4 s4 = *(const float4*)(sb + gy*W_ + gx);
            float4 m4 = *(const float4*)(mb + gy*W_ + gx);
            float tt, d;
            tt = fminf(fmaxf(s4.x*m4.x, 0.f), 1.f); d = 0.5f*(float)cls[0] - tt; lacc += d*d;
            tt = fminf(fmaxf(s4.y*m4.y, 0.f), 1.f); d = 0.5f*(float)cls[1] - tt; lacc += d*d;
            tt = fminf(fmaxf(s4.z*m4.z, 0.f), 1.f); d = 0.5f*(float)cls[2] - tt; lacc += d*d;
            tt = fminf(fmaxf(s4.w*m4.w, 0.f), 1.f); d = 0.5f*(float)cls[3] - tt; lacc += d*d;
        }
        #pragma unroll
        for (int off = 32; off > 0; off >>= 1)
            lacc += __shfl_down(lacc, off, 64);
        if ((tid & 63) == 0) wsum[tid >> 6] = lacc;
    }
    __syncthreads();
    if (tid == 0) {
        int bid = (blockIdx.z * gridDim.y + blockIdx.y) * gridDim.x + blockIdx.x;
        partials[bid] = wsum[0] + wsum[1] + wsum[2] + wsum[3];
    }
}

__global__ __launch_bounds__(256)
void k_final(const float* __restrict__ partials, float* __restrict__ out) {
    int tid = threadIdx.x;
    float acc = 0.f;
    #pragma unroll
    for (int j = 0; j < NBLK/256; ++j) acc += partials[j*256 + tid];
    #pragma unroll
    for (int off = 32; off > 0; off >>= 1)
        acc += __shfl_down(acc, off, 64);
    __shared__ float ws[4];
    if ((tid & 63) == 0) ws[tid >> 6] = acc;
    __syncthreads();
    if (tid == 0) out[0] = (ws[0] + ws[1] + ws[2] + ws[3]) * (1.0f / (float)N_);
}

extern "C" void kernel_launch(void* const* d_in, const int* in_sizes, int n_in,
                              void* d_out, int out_size, void* d_ws, size_t ws_size,
                              hipStream_t stream) {
    const float* pred   = (const float*)d_in[0];
    const float* sketch = (const float*)d_in[1];
    const float* matte  = (const float*)d_in[2];
    float* out = (float*)d_out;
    float* partials = (float*)d_ws;   // NBLK floats

    dim3 blk(256);
    dim3 grd(W_/TX, H_/TY, B_);   // (8, 16, 16) = 2048 blocks
    k_canny<<<grd, blk, 0, stream>>>(pred, sketch, matte, partials);
    k_final<<<1, blk, 0, stream>>>(partials, out);
}

// Round 8
// 58.434 us; speedup vs baseline: 1.2645x; 1.2645x over previous
//
#include <hip/hip_runtime.h>
#include <stdint.h>

#define B_  16
#define H_  512
#define W_  512
#define HW_ (H_*W_)
#define N_  (B_*HW_)

#define TX 64
#define TY 32
#define NBLK 2048

#define G0 0.054488685f
#define G1 0.244201342f
#define G2 0.402619947f

// LDS planes:
// g    [42][74] f32 : row0 y=ty0-5 (reflect-staged), col0 x=tx0-5 (reflect-staged)
// t    [42][72] f32 : row0 y=ty0-5, col0 x=tx0-3 (cols 0..69 valid)
// blur [38][72] f32 : row0 y=ty0-3, col0 x=tx0-3 (cols 0..69 valid)
// mag  [36][68] f32 : row0 y=ty0-2, col0 x=tx0-2 (squared magnitude)
// off  [36][68] i8  : NMS neighbor delta in mag-plane elems (+-1,+-67,+-68,+-69)

__device__ __forceinline__ int reflect512(int i) {
    i = i < 0 ? -i : i;
    return i > 511 ? 1022 - i : i;
}
__device__ __forceinline__ int clamp511(int v) {
    return v < 0 ? 0 : (v > 511 ? 511 : v);
}

__global__ __launch_bounds__(256)
void k_canny(const float* __restrict__ pred, const float* __restrict__ sketch,
             const float* __restrict__ matte, float* __restrict__ partials) {
    __shared__ __align__(16) union { float g[42*74]; float blur[38*72]; } uA;
    __shared__ __align__(16) union { float t[42*72]; float mag[36*68]; } uT;
    __shared__ int8_t sOff[36*68];
    __shared__ float wsum[4];

    const int tid = threadIdx.x;
    const int tx0 = blockIdx.x * TX;
    const int ty0 = blockIdx.y * TY;
    const int b   = blockIdx.z;
    const bool xint = (blockIdx.x >= 1) & (blockIdx.x <= 6);
    const bool yint = (blockIdx.y >= 1) & (blockIdx.y <= 14);

    const float* pb = pred   + (size_t)b * 3 * HW_;
    const float* mb = matte  + (size_t)b * HW_;
    const float* sb = sketch + (size_t)b * HW_;

    // hoisted loss-term loads (independent of the whole stencil pipeline)
    const int er0 = tid >> 4, eq0 = tid & 15;
    const float* sp0 = sb + (ty0 + er0)*W_ + tx0 + eq0*4;
    const float* mp0 = mb + (ty0 + er0)*W_ + tx0 + eq0*4;
    float4 s4a = *(const float4*)(sp0);
    float4 m4a = *(const float4*)(mp0);
    float4 s4b = *(const float4*)(sp0 + 16*W_);
    float4 m4b = *(const float4*)(mp0 + 16*W_);

    // ---- A: gray = mean3(pred)*matte, reflect-staged -> g[42][74] ----
    if (xint) {
        for (int u = tid; u < 840; u += 256) {
            int r = u / 20, q = u - (u / 20) * 20;
            int ys = reflect512(ty0 - 5 + r);
            int gx = tx0 - 8 + 4*q;
            const float* prow = pb + ys*W_ + gx;
            float4 p0 = *(const float4*)(prow);
            float4 p1 = *(const float4*)(prow + HW_);
            float4 p2 = *(const float4*)(prow + 2*HW_);
            float4 m4 = *(const float4*)(mb + ys*W_ + gx);
            float v[4];
            v[0] = (p0.x+p1.x+p2.x)*m4.x*(1.f/3.f);
            v[1] = (p0.y+p1.y+p2.y)*m4.y*(1.f/3.f);
            v[2] = (p0.z+p1.z+p2.z)*m4.z*(1.f/3.f);
            v[3] = (p0.w+p1.w+p2.w)*m4.w*(1.f/3.f);
            int base = r*74 + 4*q - 3;
            #pragma unroll
            for (int e2 = 0; e2 < 4; ++e2) {
                int gc = 4*q + e2 - 3;
                if ((unsigned)gc < 74u) uA.g[base + e2] = v[e2];
            }
        }
    } else {
        for (int u = tid; u < 840; u += 256) {
            int r = u / 20, q = u - (u / 20) * 20;
            int ys = reflect512(ty0 - 5 + r);
            #pragma unroll
            for (int e2 = 0; e2 < 4; ++e2) {
                int gc = 4*q + e2 - 3;
                if ((unsigned)gc < 74u) {
                    int xs = reflect512(tx0 - 5 + gc);
                    int o  = ys*W_ + xs;
                    uA.g[r*74 + gc] = (pb[o] + pb[o+HW_] + pb[o+2*HW_]) * mb[o] * (1.f/3.f);
                }
            }
        }
    }
    __syncthreads();

    // ---- B1: horizontal gaussian -> t[42][72] (cols 0..69) ----
    if (xint) {
        for (int u = tid; u < 2940; u += 256) {
            int ly = u / 70, lx = u - (u / 70) * 70;
            int gi = ly*74 + lx;
            uT.t[ly*72 + lx] = G0*(uA.g[gi] + uA.g[gi+4])
                             + G1*(uA.g[gi+1] + uA.g[gi+3])
                             + G2*uA.g[gi+2];
        }
    } else {
        for (int u = tid; u < 2940; u += 256) {
            int ly = u / 70, lx = u - (u / 70) * 70;
            int xc = clamp511(tx0 - 3 + lx) - tx0 + 5;   // center gcol in [5,68]
            int gi = ly*74 + xc;
            uT.t[ly*72 + lx] = G0*(uA.g[gi-2] + uA.g[gi+2])
                             + G1*(uA.g[gi-1] + uA.g[gi+1])
                             + G2*uA.g[gi];
        }
    }
    __syncthreads();

    // ---- B2: vertical gaussian -> blur[38][72], flat-quad b128 ----
    if (yint) {
        for (int j = tid; j < 684; j += 256) {      // 38 rows x 18 quads
            int r = j / 18, k = j - (j / 18) * 18;
            int base = r*72 + 4*k;
            float4 a = *(float4*)&uT.t[base];
            float4 bq = *(float4*)&uT.t[base + 72];
            float4 c = *(float4*)&uT.t[base + 144];
            float4 d = *(float4*)&uT.t[base + 216];
            float4 e = *(float4*)&uT.t[base + 288];
            float4 o;
            o.x = G0*(a.x+e.x) + G1*(bq.x+d.x) + G2*c.x;
            o.y = G0*(a.y+e.y) + G1*(bq.y+d.y) + G2*c.y;
            o.z = G0*(a.z+e.z) + G1*(bq.z+d.z) + G2*c.z;
            o.w = G0*(a.w+e.w) + G1*(bq.w+d.w) + G2*c.w;
            *(float4*)&uA.blur[base] = o;
        }
    } else {
        for (int u = tid; u < 2660; u += 256) {     // 38 rows x 70 cols
            int r = u / 70, c = u - (u / 70) * 70;
            int yc = clamp511(ty0 - 3 + r) - ty0 + 5;   // center t-row in [2,39]
            int ti = (yc-2)*72 + c;
            uA.blur[r*72 + c] = G0*(uT.t[ti] + uT.t[ti+288])
                              + G1*(uT.t[ti+72] + uT.t[ti+216])
                              + G2*uT.t[ti+144];
        }
    }
    __syncthreads();

    // ---- C: sobel -> mag2[36][68] + off[36][68], flat-quad reads ----
    if (xint & yint) {
        for (int j = tid; j < 612; j += 256) {      // 36 rows x 17 quads
            int r = j / 17, k = j - (j / 17) * 17;
            int bb = r*72 + 4*k;                    // blur quad at (row r, bcol 4k)
            float4 a0 = *(float4*)&uA.blur[bb];
            float4 a1 = *(float4*)&uA.blur[bb+4];
            float4 b0 = *(float4*)&uA.blur[bb+72];
            float4 b1 = *(float4*)&uA.blur[bb+76];
            float4 c0 = *(float4*)&uA.blur[bb+144];
            float4 c1 = *(float4*)&uA.blur[bb+148];
            float wa[8] = {a0.x,a0.y,a0.z,a0.w, a1.x,a1.y,a1.z,a1.w};
            float wb[8] = {b0.x,b0.y,b0.z,b0.w, b1.x,b1.y,b1.z,b1.w};
            float wc[8] = {c0.x,c0.y,c0.z,c0.w, c1.x,c1.y,c1.z,c1.w};
            float4 m2v; int ov[4];
            #pragma unroll
            for (int e2 = 0; e2 < 4; ++e2) {
                float a00 = wa[e2], a01 = wa[e2+1], a02 = wa[e2+2];
                float a10 = wb[e2],                 a12 = wb[e2+2];
                float a20 = wc[e2], a21 = wc[e2+1], a22 = wc[e2+2];
                float gxv = (a02 + 2.f*a12 + a22) - (a00 + 2.f*a10 + a20);
                float gyv = (a20 + 2.f*a21 + a22) - (a00 + 2.f*a01 + a02);
                ((float*)&m2v)[e2] = fmaf(gxv*gxv + gyv*gyv, 0.015625f, 1e-6f);
                float agx = fabsf(gxv), agy = fabsf(gyv);
                int off;
                if      (agy <= 0.41421356f*agx) off = (gxv >= 0.f) ? 1 : -1;
                else if (agy >= 2.41421356f*agx) off = (gyv > 0.f) ? -68 : 68;
                else off = ((gyv > 0.f) ? -68 : 68) + ((gxv > 0.f) ? 1 : -1);
                ov[e2] = off;
            }
            int mi = r*68 + 4*k;
            *(float4*)&uT.mag[mi] = m2v;
            uint32_t ow = (uint32_t)(uint8_t)(int8_t)ov[0]
                        | ((uint32_t)(uint8_t)(int8_t)ov[1] << 8)
                        | ((uint32_t)(uint8_t)(int8_t)ov[2] << 16)
                        | ((uint32_t)(uint8_t)(int8_t)ov[3] << 24);
            *(uint32_t*)&sOff[mi] = ow;
        }
    } else {
        for (int u = tid; u < 2448; u += 256) {     // 36 rows x 68 cols
            int r = u / 68, c = u - (u / 68) * 68;
            int y = ty0 - 2 + r, x = tx0 - 2 + c;
            float m2 = 0.f; int off = 1;
            if ((unsigned)y < 512u && (unsigned)x < 512u) {
                int r0 = clamp511(y-1) - ty0 + 3;
                int r1 = y - ty0 + 3;
                int r2 = clamp511(y+1) - ty0 + 3;
                int cm = clamp511(x-1) - tx0 + 3;
                int cc = x - tx0 + 3;
                int cp = clamp511(x+1) - tx0 + 3;
                float a00 = uA.blur[r0*72+cm], a01 = uA.blur[r0*72+cc], a02 = uA.blur[r0*72+cp];
                float a10 = uA.blur[r1*72+cm],                          a12 = uA.blur[r1*72+cp];
                float a20 = uA.blur[r2*72+cm], a21 = uA.blur[r2*72+cc], a22 = uA.blur[r2*72+cp];
                float gxv = (a02 + 2.f*a12 + a22) - (a00 + 2.f*a10 + a20);
                float gyv = (a20 + 2.f*a21 + a22) - (a00 + 2.f*a01 + a02);
                m2 = fmaf(gxv*gxv + gyv*gyv, 0.015625f, 1e-6f);
                float agx = fabsf(gxv), agy = fabsf(gyv);
                if      (agy <= 0.41421356f*agx) off = (gxv >= 0.f) ? 1 : -1;
                else if (agy >= 2.41421356f*agx) off = (gyv > 0.f) ? -68 : 68;
                else off = ((gyv > 0.f) ? -68 : 68) + ((gxv > 0.f) ? 1 : -1);
            }
            uT.mag[r*68 + c] = m2;
            sOff[r*68 + c] = (int8_t)off;
        }
    }
    __syncthreads();

    // ---- E: NMS + threshold + guarded hysteresis + MSE (D merged in) ----
    {
        float lacc = 0.f;
        #pragma unroll
        for (int half = 0; half < 2; ++half) {
            int uq = tid + half*256;
            int r = uq >> 4, q16 = uq & 15;
            int mi = (r+2)*68 + 4*q16 + 2;
            float4 s4 = half ? s4b : s4a;
            float4 m4 = half ? m4b : m4a;
            float sv[4] = {s4.x, s4.y, s4.z, s4.w};
            float mv[4] = {m4.x, m4.y, m4.z, m4.w};
            #pragma unroll
            for (int e2 = 0; e2 < 4; ++e2) {
                int mi2 = mi + e2;
                float m2 = uT.mag[mi2];
                int off = (int)sOff[mi2];
                float n1 = uT.mag[mi2 + off];
                float n2 = uT.mag[mi2 - off];
                int cls = 0;
                if (m2 > n1 && m2 > n2) cls = (m2 > 0.01f) + (m2 > 0.04f);
                if (cls == 1) {
                    bool pr = false;
                    const int dl[8] = {-69,-68,-67,-1,1,67,68,69};
                    #pragma unroll
                    for (int dd = 0; dd < 8; ++dd) {
                        int nmi = mi2 + dl[dd];
                        float nm2 = uT.mag[nmi];
                        if (nm2 > 0.04f) {
                            int noff = (int)sOff[nmi];
                            if (nm2 > uT.mag[nmi+noff] && nm2 > uT.mag[nmi-noff]) pr = true;
                        }
                    }
                    if (pr) cls = 2;
                }
                float tt = fminf(fmaxf(sv[e2]*mv[e2], 0.f), 1.f);
                float d = 0.5f*(float)cls - tt;
                lacc += d*d;
            }
        }
        #pragma unroll
        for (int off = 32; off > 0; off >>= 1)
            lacc += __shfl_down(lacc, off, 64);
        if ((tid & 63) == 0) wsum[tid >> 6] = lacc;
    }
    __syncthreads();
    if (tid == 0) {
        int bid = (blockIdx.z * gridDim.y + blockIdx.y) * gridDim.x + blockIdx.x;
        partials[bid] = wsum[0] + wsum[1] + wsum[2] + wsum[3];
    }
}

__global__ __launch_bounds__(256)
void k_final(const float* __restrict__ partials, float* __restrict__ out) {
    int tid = threadIdx.x;
    float acc = 0.f;
    #pragma unroll
    for (int j = 0; j < NBLK/256; ++j) acc += partials[j*256 + tid];
    #pragma unroll
    for (int off = 32; off > 0; off >>= 1)
        acc += __shfl_down(acc, off, 64);
    __shared__ float ws[4];
    if ((tid & 63) == 0) ws[tid >> 6] = acc;
    __syncthreads();
    if (tid == 0) out[0] = (ws[0] + ws[1] + ws[2] + ws[3]) * (1.0f / (float)N_);
}

extern "C" void kernel_launch(void* const* d_in, const int* in_sizes, int n_in,
                              void* d_out, int out_size, void* d_ws, size_t ws_size,
                              hipStream_t stream) {
    const float* pred   = (const float*)d_in[0];
    const float* sketch = (const float*)d_in[1];
    const float* matte  = (const float*)d_in[2];
    float* out = (float*)d_out;
    float* partials = (float*)d_ws;   // NBLK floats

    dim3 blk(256);
    dim3 grd(W_/TX, H_/TY, B_);   // (8, 16, 16) = 2048 blocks
    k_canny<<<grd, blk, 0, stream>>>(pred, sketch, matte, partials);
    k_final<<<1, blk, 0, stream>>>(partials, out);
}

// Round 9
// 48.134 us; speedup vs baseline: 1.5351x; 1.2140x over previous
//
#include <hip/hip_runtime.h>
#include <stdint.h>

#define B_  16
#define H_  512
#define W_  512
#define HW_ (H_*W_)
#define N_  (B_*HW_)

#define TX 64
#define TY 16
#define NBLK 4096

// plane geometry (flat-indexed), identical layout to the proven round-6 kernel,
// row counts re-derived for TY=16
#define GYr 26
#define GXc 80     // gray: rows ty0-5.., cols tx0-8..
#define TWYr 26
#define TWXc 70    // t: rows ty0-5.., cols tx0-3..
#define BLYr 22
#define BLXc 70    // blur: rows ty0-3.., cols tx0-3..
#define MGYr 20
#define MGXc 68    // mag/soff: rows ty0-2.., cols tx0-2..
#define EYr 18
#define EXc 66     // e: rows ty0-1.., cols tx0-1..

#define G0 0.054488685f
#define G1 0.244201342f
#define G2 0.402619947f

__device__ __forceinline__ int reflect512(int i) {
    i = i < 0 ? -i : i;
    return i > 511 ? 1022 - i : i;
}
__device__ __forceinline__ int clamp511(int v) {
    return v < 0 ? 0 : (v > 511 ? 511 : v);
}

__global__ __launch_bounds__(256)
void k_canny(const float* __restrict__ pred, const float* __restrict__ sketch,
             const float* __restrict__ matte, float* __restrict__ partials) {
    // g (8320B) / blur (6160B) / e (4752B) are pairwise non-overlapping in time
    __shared__ __align__(16) union {
        float g[GYr*GXc];
        float blur[BLYr*BLXc];
        int   e[EYr*EXc];
    } uA;
    // t (7280B) / mag (5440B)
    __shared__ __align__(16) union {
        float t[TWYr*TWXc];
        float mag[MGYr*MGXc];
    } uT;
    __shared__ int16_t sOff[MGYr*MGXc];
    __shared__ float wsum[4];

    const int tid = threadIdx.x;
    const int tx0 = blockIdx.x * TX;
    const int ty0 = blockIdx.y * TY;
    const int b   = blockIdx.z;
    const bool interior = (blockIdx.x >= 1) & (blockIdx.x <= 6) &
                          (blockIdx.y >= 1) & (blockIdx.y <= 30);

    const float* pb = pred   + (size_t)b * 3 * HW_;
    const float* mb = matte  + (size_t)b * HW_;
    const float* sb = sketch + (size_t)b * HW_;

    // ---- A: gray = mean3(pred)*matte, reflect-staged, 26x80, float4 quads ----
    {
        const bool xfast = (tx0 >= 8) && (tx0 + 71 < W_);
        for (int u = tid; u < GYr*20; u += 256) {
            int r = u / 20, q = u - r*20;
            int ys = reflect512(ty0 - 5 + r);
            int gx = tx0 - 8 + q*4;
            float4 res;
            if (xfast) {
                const float* prow = pb + ys*W_ + gx;
                float4 p0 = *(const float4*)(prow);
                float4 p1 = *(const float4*)(prow + HW_);
                float4 p2 = *(const float4*)(prow + 2*HW_);
                float4 m4 = *(const float4*)(mb + ys*W_ + gx);
                res.x = (p0.x+p1.x+p2.x)*m4.x*(1.f/3.f);
                res.y = (p0.y+p1.y+p2.y)*m4.y*(1.f/3.f);
                res.z = (p0.z+p1.z+p2.z)*m4.z*(1.f/3.f);
                res.w = (p0.w+p1.w+p2.w)*m4.w*(1.f/3.f);
            } else {
                float tmp[4];
                #pragma unroll
                for (int e2 = 0; e2 < 4; ++e2) {
                    int xs = reflect512(gx + e2);
                    int o  = ys*W_ + xs;
                    tmp[e2] = (pb[o] + pb[o+HW_] + pb[o+2*HW_]) * mb[o] * (1.f/3.f);
                }
                res.x = tmp[0]; res.y = tmp[1]; res.z = tmp[2]; res.w = tmp[3];
            }
            *(float4*)&uA.g[4*u] = res;   // r*80 + q*4 == 4u
        }
    }
    __syncthreads();

    // ---- B1: horizontal gaussian -> t [26][70] ----
    {
        int r = tid / TWXc, c = tid - (tid / TWXc) * TWXc;
        if (interior) {
            #pragma unroll
            for (int it = 0; it < 8; ++it) {
                if (r < TWYr) {
                    int gi = r*GXc + c + 3;      // g col (c+5) - 2
                    uT.t[r*TWXc + c] =
                        G0*uA.g[gi] + G1*uA.g[gi+1] + G2*uA.g[gi+2]
                      + G1*uA.g[gi+3] + G0*uA.g[gi+4];
                }
                c += 46; r += 3; if (c >= TWXc) { c -= TWXc; ++r; }
            }
        } else {
            #pragma unroll
            for (int it = 0; it < 8; ++it) {
                if (r < TWYr) {
                    int xc = clamp511(tx0 - 3 + c) - (tx0 - 8);
                    int gi = r*GXc + xc;
                    uT.t[r*TWXc + c] =
                        G0*uA.g[gi-2] + G1*uA.g[gi-1] + G2*uA.g[gi]
                      + G1*uA.g[gi+1] + G0*uA.g[gi+2];
                }
                c += 46; r += 3; if (c >= TWXc) { c -= TWXc; ++r; }
            }
        }
    }
    __syncthreads();

    // ---- B2: vertical gaussian -> blur [22][70] (aliases g) ----
    {
        int r = tid / BLXc, c = tid - (tid / BLXc) * BLXc;
        if (interior) {
            #pragma unroll
            for (int it = 0; it < 7; ++it) {
                if (r < BLYr) {
                    int ti = r*TWXc + c;         // t row (r+2) - 2
                    uA.blur[r*BLXc + c] =
                        G0*uT.t[ti] + G1*uT.t[ti+70] + G2*uT.t[ti+140]
                      + G1*uT.t[ti+210] + G0*uT.t[ti+280];
                }
                c += 46; r += 3; if (c >= BLXc) { c -= BLXc; ++r; }
            }
        } else {
            #pragma unroll
            for (int it = 0; it < 7; ++it) {
                if (r < BLYr) {
                    int yc = clamp511(ty0 - 3 + r) - (ty0 - 5);   // [2,23]
                    int ti = (yc-2)*TWXc + c;
                    uA.blur[r*BLXc + c] =
                        G0*uT.t[ti] + G1*uT.t[ti+70] + G2*uT.t[ti+140]
                      + G1*uT.t[ti+210] + G0*uT.t[ti+280];
                }
                c += 46; r += 3; if (c >= BLXc) { c -= BLXc; ++r; }
            }
        }
    }
    __syncthreads();

    // ---- C: sobel -> mag2 [20][68] (aliases t) + NMS offset ----
    {
        int r = tid / MGXc, c = tid - (tid / MGXc) * MGXc;
        if (interior) {
            #pragma unroll
            for (int it = 0; it < 6; ++it) {
                if (r < MGYr) {
                    int bi = r*BLXc + c;
                    float a00 = uA.blur[bi],     a01 = uA.blur[bi+1],   a02 = uA.blur[bi+2];
                    float a10 = uA.blur[bi+70],                         a12 = uA.blur[bi+72];
                    float a20 = uA.blur[bi+140], a21 = uA.blur[bi+141], a22 = uA.blur[bi+142];
                    float gxv = (a02 + 2.f*a12 + a22) - (a00 + 2.f*a10 + a20);
                    float gyv = (a20 + 2.f*a21 + a22) - (a00 + 2.f*a01 + a02);
                    float m2  = fmaf(gxv*gxv + gyv*gyv, 0.015625f, 1e-6f);
                    float agx = fabsf(gxv), agy = fabsf(gyv);
                    int off;
                    if      (agy <= 0.41421356f * agx) off = (gxv >= 0.f) ? 1 : -1;
                    else if (agy >= 2.41421356f * agx) off = (gyv >  0.f) ? -MGXc : MGXc;
                    else off = ((gyv > 0.f) ? -MGXc : MGXc) + ((gxv > 0.f) ? 1 : -1);
                    int mi = r*MGXc + c;
                    uT.mag[mi] = m2;
                    sOff[mi] = (int16_t)off;
                }
                c += 52; r += 3; if (c >= MGXc) { c -= MGXc; ++r; }
            }
        } else {
            #pragma unroll
            for (int it = 0; it < 6; ++it) {
                if (r < MGYr) {
                    int y = ty0 - 2 + r, x = tx0 - 2 + c;
                    float m2 = 0.f; int off = 0;
                    if ((unsigned)y < 512u && (unsigned)x < 512u) {
                        int r0 = clamp511(y-1) - (ty0-3);
                        int r1 = y - (ty0-3);
                        int r2 = clamp511(y+1) - (ty0-3);
                        int cm = clamp511(x-1) - (tx0-3);
                        int cc = x - (tx0-3);
                        int cp = clamp511(x+1) - (tx0-3);
                        float a00 = uA.blur[r0*BLXc+cm], a01 = uA.blur[r0*BLXc+cc], a02 = uA.blur[r0*BLXc+cp];
                        float a10 = uA.blur[r1*BLXc+cm],                            a12 = uA.blur[r1*BLXc+cp];
                        float a20 = uA.blur[r2*BLXc+cm], a21 = uA.blur[r2*BLXc+cc], a22 = uA.blur[r2*BLXc+cp];
                        float gxv = (a02 + 2.f*a12 + a22) - (a00 + 2.f*a10 + a20);
                        float gyv = (a20 + 2.f*a21 + a22) - (a00 + 2.f*a01 + a02);
                        m2 = fmaf(gxv*gxv + gyv*gyv, 0.015625f, 1e-6f);
                        float agx = fabsf(gxv), agy = fabsf(gyv);
                        if      (agy <= 0.41421356f * agx) off = (gxv >= 0.f) ? 1 : -1;
                        else if (agy >= 2.41421356f * agx) off = (gyv >  0.f) ? -MGXc : MGXc;
                        else off = ((gyv > 0.f) ? -MGXc : MGXc) + ((gxv > 0.f) ? 1 : -1);
                    }
                    int mi = r*MGXc + c;
                    uT.mag[mi] = m2;
                    sOff[mi] = (int16_t)off;
                }
                c += 52; r += 3; if (c >= MGXc) { c -= MGXc; ++r; }
            }
        }
    }
    __syncthreads();

    // ---- D: NMS + double threshold -> class [18][66] (aliases g/blur) ----
    {
        int r = tid / EXc, c = tid - (tid / EXc) * EXc;
        #pragma unroll
        for (int it = 0; it < 5; ++it) {
            if (r < EYr) {
                int mi = r*MGXc + c + MGXc + 1;     // center
                float m2 = uT.mag[mi];
                int off = (int)sOff[mi];
                float n1 = uT.mag[mi + off];
                float n2 = uT.mag[mi - off];
                int cls = 0;
                if (m2 > n1 && m2 > n2) cls = (m2 > 0.01f) + (m2 > 0.04f);
                uA.e[r*EXc + c] = cls;
            }
            c += 58; r += 3; if (c >= EXc) { c -= EXc; ++r; }
        }
    }
    __syncthreads();

    // ---- E: guarded 1-sweep hysteresis + MSE, exactly 1 quad/thread ----
    {
        float lacc = 0.f;
        int r = tid >> 4, q16 = tid & 15;
        int gy = ty0 + r, gx = tx0 + q16*4;
        int ei = (r+1)*EXc + q16*4 + 1;
        int cls[4];
        #pragma unroll
        for (int j = 0; j < 4; ++j) cls[j] = uA.e[ei+j];
        if (cls[0] == 1 || cls[1] == 1 || cls[2] == 1 || cls[3] == 1) {
            #pragma unroll
            for (int j = 0; j < 4; ++j) {
                if (cls[j] == 1) {
                    int cc = ei + j;
                    bool pr = (uA.e[cc-EXc-1] == 2) | (uA.e[cc-EXc] == 2) | (uA.e[cc-EXc+1] == 2)
                            | (uA.e[cc-1]     == 2) |                       (uA.e[cc+1]     == 2)
                            | (uA.e[cc+EXc-1] == 2) | (uA.e[cc+EXc] == 2) | (uA.e[cc+EXc+1] == 2);
                    if (pr) cls[j] = 2;
                }
            }
        }
        float4 s4 = *(const float4*)(sb + gy*W_ + gx);
        float4 m4 = *(const float4*)(mb + gy*W_ + gx);
        float tt, d;
        tt = fminf(fmaxf(s4.x*m4.x, 0.f), 1.f); d = 0.5f*(float)cls[0] - tt; lacc += d*d;
        tt = fminf(fmaxf(s4.y*m4.y, 0.f), 1.f); d = 0.5f*(float)cls[1] - tt; lacc += d*d;
        tt = fminf(fmaxf(s4.z*m4.z, 0.f), 1.f); d = 0.5f*(float)cls[2] - tt; lacc += d*d;
        tt = fminf(fmaxf(s4.w*m4.w, 0.f), 1.f); d = 0.5f*(float)cls[3] - tt; lacc += d*d;

        #pragma unroll
        for (int off = 32; off > 0; off >>= 1)
            lacc += __shfl_down(lacc, off, 64);
        if ((tid & 63) == 0) wsum[tid >> 6] = lacc;
    }
    __syncthreads();
    if (tid == 0) {
        int bid = (blockIdx.z * gridDim.y + blockIdx.y) * gridDim.x + blockIdx.x;
        partials[bid] = wsum[0] + wsum[1] + wsum[2] + wsum[3];
    }
}

__global__ __launch_bounds__(256)
void k_final(const float* __restrict__ partials, float* __restrict__ out) {
    int tid = threadIdx.x;
    float acc = 0.f;
    #pragma unroll
    for (int j = 0; j < NBLK/256; ++j) acc += partials[j*256 + tid];
    #pragma unroll
    for (int off = 32; off > 0; off >>= 1)
        acc += __shfl_down(acc, off, 64);
    __shared__ float ws[4];
    if ((tid & 63) == 0) ws[tid >> 6] = acc;
    __syncthreads();
    if (tid == 0) out[0] = (ws[0] + ws[1] + ws[2] + ws[3]) * (1.0f / (float)N_);
}

extern "C" void kernel_launch(void* const* d_in, const int* in_sizes, int n_in,
                              void* d_out, int out_size, void* d_ws, size_t ws_size,
                              hipStream_t stream) {
    const float* pred   = (const float*)d_in[0];
    const float* sketch = (const float*)d_in[1];
    const float* matte  = (const float*)d_in[2];
    float* out = (float*)d_out;
    float* partials = (float*)d_ws;   // NBLK floats

    dim3 blk(256);
    dim3 grd(W_/TX, H_/TY, B_);   // (8, 32, 16) = 4096 blocks
    k_canny<<<grd, blk, 0, stream>>>(pred, sketch, matte, partials);
    k_final<<<1, blk, 0, stream>>>(partials, out);
}

// Round 10
// 48.114 us; speedup vs baseline: 1.5358x; 1.0004x over previous
//
#include <hip/hip_runtime.h>
#include <stdint.h>

#define B_  16
#define H_  512
#define W_  512
#define HW_ (H_*W_)
#define N_  (B_*HW_)

#define TX 64
#define TY 16
#define NBLK 4096

// plane geometry (flat-indexed)
#define GYr 26
#define GXc 80     // gray: rows ty0-5.., cols tx0-8..  (reflect-staged)
#define TWYr 26
#define TWXc 72    // t: rows ty0-5.., cols tx0-3.. (cols 0..71 written interior, 0..69 boundary)
#define BLYr 22
#define BLXc 72    // blur: rows ty0-3.., cols tx0-3..
#define MGYr 20
#define MGXc 68    // mag/soff: rows ty0-2.., cols tx0-2..
#define EYr 18
#define EXc 66     // e: rows ty0-1.., cols tx0-1..

#define G0 0.054488685f
#define G1 0.244201342f
#define G2 0.402619947f

__device__ __forceinline__ int reflect512(int i) {
    i = i < 0 ? -i : i;
    return i > 511 ? 1022 - i : i;
}
__device__ __forceinline__ int clamp511(int v) {
    return v < 0 ? 0 : (v > 511 ? 511 : v);
}

__global__ __launch_bounds__(256)
void k_canny(const float* __restrict__ pred, const float* __restrict__ sketch,
             const float* __restrict__ matte, float* __restrict__ partials) {
    // g / blur / e pairwise non-overlapping in time
    __shared__ __align__(16) union {
        float g[GYr*GXc];       // 8320 B
        float blur[BLYr*BLXc];  // 6336 B
        int   e[EYr*EXc];       // 4752 B
    } uA;
    __shared__ __align__(16) union {
        float t[TWYr*TWXc];     // 7488 B
        float mag[MGYr*MGXc];   // 5440 B
    } uT;
    __shared__ __align__(8) int16_t sOff[MGYr*MGXc];
    __shared__ float wsum[4];

    const int tid = threadIdx.x;
    const int tx0 = blockIdx.x * TX;
    const int ty0 = blockIdx.y * TY;
    const int b   = blockIdx.z;
    const bool interior = (blockIdx.x >= 1) & (blockIdx.x <= 6) &
                          (blockIdx.y >= 1) & (blockIdx.y <= 30);

    const float* pb = pred   + (size_t)b * 3 * HW_;
    const float* mb = matte  + (size_t)b * HW_;
    const float* sb = sketch + (size_t)b * HW_;

    // ---- A: gray = mean3(pred)*matte, reflect-staged, 26x80 (identical to r9) ----
    {
        const bool xfast = (tx0 >= 8) && (tx0 + 71 < W_);
        for (int u = tid; u < GYr*20; u += 256) {
            int r = u / 20, q = u - r*20;
            int ys = reflect512(ty0 - 5 + r);
            int gx = tx0 - 8 + q*4;
            float4 res;
            if (xfast) {
                const float* prow = pb + ys*W_ + gx;
                float4 p0 = *(const float4*)(prow);
                float4 p1 = *(const float4*)(prow + HW_);
                float4 p2 = *(const float4*)(prow + 2*HW_);
                float4 m4 = *(const float4*)(mb + ys*W_ + gx);
                res.x = (p0.x+p1.x+p2.x)*m4.x*(1.f/3.f);
                res.y = (p0.y+p1.y+p2.y)*m4.y*(1.f/3.f);
                res.z = (p0.z+p1.z+p2.z)*m4.z*(1.f/3.f);
                res.w = (p0.w+p1.w+p2.w)*m4.w*(1.f/3.f);
            } else {
                float tmp[4];
                #pragma unroll
                for (int e2 = 0; e2 < 4; ++e2) {
                    int xs = reflect512(gx + e2);
                    int o  = ys*W_ + xs;
                    tmp[e2] = (pb[o] + pb[o+HW_] + pb[o+2*HW_]) * mb[o] * (1.f/3.f);
                }
                res.x = tmp[0]; res.y = tmp[1]; res.z = tmp[2]; res.w = tmp[3];
            }
            *(float4*)&uA.g[4*u] = res;   // r*80 + q*4 == 4u
        }
    }
    __syncthreads();

    // ---- B1: horizontal gaussian -> t ----
    if (interior) {
        // quad form: 26 rows x 18 quads; 3 aligned b128 reads -> 1 b128 write
        for (int u = tid; u < 468; u += 256) {
            int r = u / 18, k = u - (u / 18) * 18;
            const float* gq = &uA.g[r*GXc + 4*k];
            float4 q0 = *(const float4*)(gq);
            float4 q1 = *(const float4*)(gq + 4);
            float4 q2 = *(const float4*)(gq + 8);
            float4 o;
            o.x = G0*(q0.w + q1.w) + G1*(q1.x + q1.z) + G2*q1.y;
            o.y = G0*(q1.x + q2.x) + G1*(q1.y + q1.w) + G2*q1.z;
            o.z = G0*(q1.y + q2.y) + G1*(q1.z + q2.x) + G2*q1.w;
            o.w = G0*(q1.z + q2.z) + G1*(q1.w + q2.y) + G2*q2.x;
            *(float4*)&uT.t[r*TWXc + 4*k] = o;
        }
    } else {
        int r = tid / 70, c = tid - (tid / 70) * 70;
        #pragma unroll
        for (int it = 0; it < 8; ++it) {
            if (r < TWYr) {
                int xc = clamp511(tx0 - 3 + c) - (tx0 - 8);
                int gi = r*GXc + xc;
                uT.t[r*TWXc + c] =
                    G0*(uA.g[gi-2] + uA.g[gi+2])
                  + G1*(uA.g[gi-1] + uA.g[gi+1])
                  + G2*uA.g[gi];
            }
            c += 46; r += 3; if (c >= 70) { c -= 70; ++r; }
        }
    }
    __syncthreads();

    // ---- B2: vertical gaussian -> blur ----
    if (interior) {
        // quad form: 22 rows x 18 quads; 5 column-aligned b128 reads -> 1 write
        for (int u = tid; u < 396; u += 256) {
            int r = u / 18, k = u - (u / 18) * 18;
            const float* tq = &uT.t[r*TWXc + 4*k];
            float4 a = *(const float4*)(tq);
            float4 bq = *(const float4*)(tq + TWXc);
            float4 c = *(const float4*)(tq + 2*TWXc);
            float4 d = *(const float4*)(tq + 3*TWXc);
            float4 e = *(const float4*)(tq + 4*TWXc);
            float4 o;
            o.x = G0*(a.x+e.x) + G1*(bq.x+d.x) + G2*c.x;
            o.y = G0*(a.y+e.y) + G1*(bq.y+d.y) + G2*c.y;
            o.z = G0*(a.z+e.z) + G1*(bq.z+d.z) + G2*c.z;
            o.w = G0*(a.w+e.w) + G1*(bq.w+d.w) + G2*c.w;
            *(float4*)&uA.blur[r*BLXc + 4*k] = o;
        }
    } else {
        int r = tid / 70, c = tid - (tid / 70) * 70;
        #pragma unroll
        for (int it = 0; it < 7; ++it) {
            if (r < BLYr) {
                int yc = clamp511(ty0 - 3 + r) - (ty0 - 5);   // [2,23]
                int ti = (yc-2)*TWXc + c;
                uA.blur[r*BLXc + c] =
                    G0*(uT.t[ti] + uT.t[ti+4*TWXc])
                  + G1*(uT.t[ti+TWXc] + uT.t[ti+3*TWXc])
                  + G2*uT.t[ti+2*TWXc];
            }
            c += 46; r += 3; if (c >= 70) { c -= 70; ++r; }
        }
    }
    __syncthreads();

    // ---- C: sobel -> mag2 + NMS offset ----
    if (interior) {
        // quad form: 20 rows x 17 quads; 6 b128 reads -> 1 b128 + 1 b64 write
        for (int u = tid; u < 340; u += 256) {
            int r = u / 17, k = u - (u / 17) * 17;
            const float* b0 = &uA.blur[r*BLXc + 4*k];
            float4 a0 = *(const float4*)(b0);
            float4 a1 = *(const float4*)(b0 + 4);
            float4 bq0 = *(const float4*)(b0 + BLXc);
            float4 bq1 = *(const float4*)(b0 + BLXc + 4);
            float4 c0 = *(const float4*)(b0 + 2*BLXc);
            float4 c1 = *(const float4*)(b0 + 2*BLXc + 4);
            float wa[6] = {a0.x,a0.y,a0.z,a0.w, a1.x,a1.y};
            float wb[6] = {bq0.x,bq0.y,bq0.z,bq0.w, bq1.x,bq1.y};
            float wc[6] = {c0.x,c0.y,c0.z,c0.w, c1.x,c1.y};
            float cs[6], rd[6];
            #pragma unroll
            for (int i = 0; i < 6; ++i) {
                cs[i] = wa[i] + 2.f*wb[i] + wc[i];
                rd[i] = wc[i] - wa[i];
            }
            float4 m2v; int ov[4];
            #pragma unroll
            for (int e2 = 0; e2 < 4; ++e2) {
                float gxv = cs[e2+2] - cs[e2];
                float gyv = rd[e2] + 2.f*rd[e2+1] + rd[e2+2];
                ((float*)&m2v)[e2] = fmaf(gxv*gxv + gyv*gyv, 0.015625f, 1e-6f);
                float agx = fabsf(gxv), agy = fabsf(gyv);
                int off;
                if      (agy <= 0.41421356f * agx) off = (gxv >= 0.f) ? 1 : -1;
                else if (agy >= 2.41421356f * agx) off = (gyv >  0.f) ? -MGXc : MGXc;
                else off = ((gyv > 0.f) ? -MGXc : MGXc) + ((gxv > 0.f) ? 1 : -1);
                ov[e2] = off;
            }
            int mi = r*MGXc + 4*k;
            *(float4*)&uT.mag[mi] = m2v;
            uint2 ow;
            ow.x = (uint32_t)(uint16_t)(int16_t)ov[0] | ((uint32_t)(uint16_t)(int16_t)ov[1] << 16);
            ow.y = (uint32_t)(uint16_t)(int16_t)ov[2] | ((uint32_t)(uint16_t)(int16_t)ov[3] << 16);
            *(uint2*)&sOff[mi] = ow;
        }
    } else {
        for (int u = tid; u < MGYr*MGXc; u += 256) {
            int r = u / MGXc, c = u - (u / MGXc) * MGXc;
            int y = ty0 - 2 + r, x = tx0 - 2 + c;
            float m2 = 0.f; int off = 0;
            if ((unsigned)y < 512u && (unsigned)x < 512u) {
                int r0 = clamp511(y-1) - (ty0-3);
                int r1 = y - (ty0-3);
                int r2 = clamp511(y+1) - (ty0-3);
                int cm = clamp511(x-1) - (tx0-3);
                int cc = x - (tx0-3);
                int cp = clamp511(x+1) - (tx0-3);
                float a00 = uA.blur[r0*BLXc+cm], a01 = uA.blur[r0*BLXc+cc], a02 = uA.blur[r0*BLXc+cp];
                float a10 = uA.blur[r1*BLXc+cm],                            a12 = uA.blur[r1*BLXc+cp];
                float a20 = uA.blur[r2*BLXc+cm], a21 = uA.blur[r2*BLXc+cc], a22 = uA.blur[r2*BLXc+cp];
                float gxv = (a02 + 2.f*a12 + a22) - (a00 + 2.f*a10 + a20);
                float gyv = (a20 + 2.f*a21 + a22) - (a00 + 2.f*a01 + a02);
                m2 = fmaf(gxv*gxv + gyv*gyv, 0.015625f, 1e-6f);
                float agx = fabsf(gxv), agy = fabsf(gyv);
                if      (agy <= 0.41421356f * agx) off = (gxv >= 0.f) ? 1 : -1;
                else if (agy >= 2.41421356f * agx) off = (gyv >  0.f) ? -MGXc : MGXc;
                else off = ((gyv > 0.f) ? -MGXc : MGXc) + ((gxv > 0.f) ? 1 : -1);
            }
            uT.mag[r*MGXc + c] = m2;
            sOff[r*MGXc + c] = (int16_t)off;
        }
    }
    __syncthreads();

    // ---- D: NMS + double threshold -> class [18][66] (identical to r9) ----
    {
        int r = tid / EXc, c = tid - (tid / EXc) * EXc;
        #pragma unroll
        for (int it = 0; it < 5; ++it) {
            if (r < EYr) {
                int mi = r*MGXc + c + MGXc + 1;     // center
                float m2 = uT.mag[mi];
                int off = (int)sOff[mi];
                float n1 = uT.mag[mi + off];
                float n2 = uT.mag[mi - off];
                int cls = 0;
                if (m2 > n1 && m2 > n2) cls = (m2 > 0.01f) + (m2 > 0.04f);
                uA.e[r*EXc + c] = cls;
            }
            c += 58; r += 3; if (c >= EXc) { c -= EXc; ++r; }
        }
    }
    __syncthreads();

    // ---- E: guarded 1-sweep hysteresis + MSE, 1 quad/thread (identical to r9) ----
    {
        float lacc = 0.f;
        int r = tid >> 4, q16 = tid & 15;
        int gy = ty0 + r, gx = tx0 + q16*4;
        int ei = (r+1)*EXc + q16*4 + 1;
        int cls[4];
        #pragma unroll
        for (int j = 0; j < 4; ++j) cls[j] = uA.e[ei+j];
        if (cls[0] == 1 || cls[1] == 1 || cls[2] == 1 || cls[3] == 1) {
            #pragma unroll
            for (int j = 0; j < 4; ++j) {
                if (cls[j] == 1) {
                    int cc = ei + j;
                    bool pr = (uA.e[cc-EXc-1] == 2) | (uA.e[cc-EXc] == 2) | (uA.e[cc-EXc+1] == 2)
                            | (uA.e[cc-1]     == 2) |                       (uA.e[cc+1]     == 2)
                            | (uA.e[cc+EXc-1] == 2) | (uA.e[cc+EXc] == 2) | (uA.e[cc+EXc+1] == 2);
                    if (pr) cls[j] = 2;
                }
            }
        }
        float4 s4 = *(const float4*)(sb + gy*W_ + gx);
        float4 m4 = *(const float4*)(mb + gy*W_ + gx);
        float tt, d;
        tt = fminf(fmaxf(s4.x*m4.x, 0.f), 1.f); d = 0.5f*(float)cls[0] - tt; lacc += d*d;
        tt = fminf(fmaxf(s4.y*m4.y, 0.f), 1.f); d = 0.5f*(float)cls[1] - tt; lacc += d*d;
        tt = fminf(fmaxf(s4.z*m4.z, 0.f), 1.f); d = 0.5f*(float)cls[2] - tt; lacc += d*d;
        tt = fminf(fmaxf(s4.w*m4.w, 0.f), 1.f); d = 0.5f*(float)cls[3] - tt; lacc += d*d;

        #pragma unroll
        for (int off = 32; off > 0; off >>= 1)
            lacc += __shfl_down(lacc, off, 64);
        if ((tid & 63) == 0) wsum[tid >> 6] = lacc;
    }
    __syncthreads();
    if (tid == 0) {
        int bid = (blockIdx.z * gridDim.y + blockIdx.y) * gridDim.x + blockIdx.x;
        partials[bid] = wsum[0] + wsum[1] + wsum[2] + wsum[3];
    }
}

__global__ __launch_bounds__(256)
void k_final(const float* __restrict__ partials, float* __restrict__ out) {
    int tid = threadIdx.x;
    float acc = 0.f;
    #pragma unroll
    for (int j = 0; j < NBLK/256; ++j) acc += partials[j*256 + tid];
    #pragma unroll
    for (int off = 32; off > 0; off >>= 1)
        acc += __shfl_down(acc, off, 64);
    __shared__ float ws[4];
    if ((tid & 63) == 0) ws[tid >> 6] = acc;
    __syncthreads();
    if (tid == 0) out[0] = (ws[0] + ws[1] + ws[2] + ws[3]) * (1.0f / (float)N_);
}

extern "C" void kernel_launch(void* const* d_in, const int* in_sizes, int n_in,
                              void* d_out, int out_size, void* d_ws, size_t ws_size,
                              hipStream_t stream) {
    const float* pred   = (const float*)d_in[0];
    const float* sketch = (const float*)d_in[1];
    const float* matte  = (const float*)d_in[2];
    float* out = (float*)d_out;
    float* partials = (float*)d_ws;   // NBLK floats

    dim3 blk(256);
    dim3 grd(W_/TX, H_/TY, B_);   // (8, 32, 16) = 4096 blocks
    k_canny<<<grd, blk, 0, stream>>>(pred, sketch, matte, partials);
    k_final<<<1, blk, 0, stream>>>(partials, out);
}